// Round 13
// baseline (342.306 us; speedup 1.0000x reference)
//
#include <hip/hip_runtime.h>

#define CH 128  // channels = H*D = 4*32
#define SLOTS 64  // padded per-node edge slots; P(deg>=64 | Poisson(16)) ~ 1e-19

typedef short bf16x8 __attribute__((ext_vector_type(8)));
typedef float f32x4 __attribute__((ext_vector_type(4)));
typedef float f32x2 __attribute__((ext_vector_type(2)));
typedef _Float16 f16x2 __attribute__((ext_vector_type(2)));

// ---------- helpers ----------
static __device__ __forceinline__ unsigned short f2bf(float f) {
  union { float f; unsigned int i; } c;
  c.f = f;
  unsigned int r = c.i + 0x7fffu + ((c.i >> 16) & 1u);  // RNE
  return (unsigned short)(r >> 16);
}

// fp8 e4m3 fallbacks (used only if builtins are missing)
static __device__ float fp82f_sw(unsigned int b) {
  int sgn = (b >> 7) & 1;
  int e = (b >> 3) & 15;
  int m = b & 7;
  float v = e ? ldexpf(1.f + m * 0.125f, e - 7) : ldexpf((float)m, -9);
  return sgn ? -v : v;
}
static __device__ unsigned char f2fp8_sw(float f) {
  unsigned char s = (f < 0.f) ? 0x80 : 0;
  float af = fabsf(f);
  if (!(af < 448.f)) return s | 0x7e;
  int ex;
  frexpf(af, &ex);
  int e = ex - 1;
  if (e < -6) e = -6;
  float step = ldexpf(1.f, e - 3);
  float qq = rintf(af / step);
  if (qq >= 16.f) { qq = 8.f; e += 1; }
  if (e > 8) return s | 0x7e;
  unsigned char bits = (qq < 8.f) ? (unsigned char)qq
                                  : (unsigned char)(((e + 7) << 3) | ((int)qq - 8));
  return s | bits;
}
template <bool HI>
static __device__ __forceinline__ unsigned int pkfp8(float a, float b, unsigned int old) {
#if __has_builtin(__builtin_amdgcn_cvt_pk_fp8_f32)
  return (unsigned int)__builtin_amdgcn_cvt_pk_fp8_f32(a, b, (int)old, HI);
#else
  unsigned int w = ((unsigned)f2fp8_sw(a)) | (((unsigned)f2fp8_sw(b)) << 8);
  return HI ? ((old & 0x0000ffffu) | (w << 16)) : ((old & 0xffff0000u) | w);
#endif
}
template <bool HI>
static __device__ __forceinline__ f32x2 upkfp8(unsigned int src) {
#if __has_builtin(__builtin_amdgcn_cvt_pk_f32_fp8)
  return __builtin_amdgcn_cvt_pk_f32_fp8((int)src, HI);
#else
  unsigned int h = HI ? (src >> 16) : (src & 0xffffu);
  f32x2 r;
  r[0] = fp82f_sw(h & 0xff);
  r[1] = fp82f_sw((h >> 8) & 0xff);
  return r;
#endif
}

// ---------- 1. BatchNorm statistics ----------
__global__ void bn_stats_kernel(const float* __restrict__ x, float* __restrict__ stats, int N) {
  int t = threadIdx.x;
  int ch = t & (CH - 1);
  int r0 = t >> 7;
  float s = 0.f, ss = 0.f;
  for (int row = blockIdx.x * 2 + r0; row < N; row += gridDim.x * 2) {
    float v = x[(size_t)row * CH + ch];
    s += v;
    ss += v * v;
  }
  atomicAdd(&stats[ch], s);
  atomicAdd(&stats[CH + ch], ss);
}

// ---------- 1b. pack weights: Wt[mat][n][k] bf16, mats = q,k,v,skip,fc ----------
__global__ void pack_w_kernel(const float* __restrict__ Wq, const float* __restrict__ Wk,
                              const float* __restrict__ Wv, const float* __restrict__ Ws,
                              const float* __restrict__ Wfc, unsigned short* __restrict__ Wt) {
  int el = blockIdx.x * 256 + threadIdx.x;  // 5*16384 elements
  int mat = el >> 14;
  int rem = el & 16383;
  int kk = rem >> 7;
  int n = rem & 127;
  const float* W = mat == 0 ? Wq : mat == 1 ? Wk : mat == 2 ? Wv : mat == 3 ? Ws : Wfc;
  Wt[((size_t)mat << 14) + n * 128 + kk] = f2bf(W[kk * 128 + n]);
}

// ---------- 2. fused BN+ReLU + 4 projections via MFMA ----------
// BN scale/shift derived per-block from stats. Swapped-operand MFMA; epilogue
// staged through per-wave 4KB LDS region -> full-cache-line coalesced stores.
// wave 0 -> q (f16), wave 1 -> k (fp8), wave 2 -> v (fp8), wave 3 -> skip (f16)
__global__ __launch_bounds__(256, 2) void proj_mfma_kernel(
    const float* __restrict__ x, const float* __restrict__ stats,
    const float* __restrict__ gamma, const float* __restrict__ beta,
    const unsigned short* __restrict__ Wt,
    const float* __restrict__ bq_, const float* __restrict__ bk_,
    const float* __restrict__ bv_, const float* __restrict__ bs_,
    unsigned short* __restrict__ q, unsigned char* __restrict__ k8,
    unsigned char* __restrict__ v8, unsigned short* __restrict__ s_, int N) {
  __shared__ __align__(16) unsigned short As[64 * 128];  // 16KB, XOR-swizzled
  __shared__ __align__(16) float scsh[256];
  int t = threadIdx.x;
  int lane = t & 63;
  int wid = t >> 6;
  size_t row0 = (size_t)blockIdx.x * 64;

  if (t < CH) {
    float inv_n = 1.0f / (float)N;
    float mu = stats[t] * inv_n;
    float var = stats[CH + t] * inv_n - mu * mu;
    float sc = gamma[t] * rsqrtf(var + 1e-5f);
    scsh[t] = sc;
    scsh[CH + t] = beta[t] - mu * sc;
  }
  __syncthreads();

  for (int i = 0; i < 4; ++i) {
    int c = i * 256 + t;
    int r = c >> 4;
    int kc = (c & 15) * 8;
    float4 v0 = make_float4(0.f, 0.f, 0.f, 0.f), v1 = v0;
    if (row0 + r < (size_t)N) {
      const float* g = x + (row0 + r) * CH + kc;
      v0 = *reinterpret_cast<const float4*>(g);
      v1 = *reinterpret_cast<const float4*>(g + 4);
    }
    float4 sca = *reinterpret_cast<const float4*>(scsh + kc);
    float4 scb = *reinterpret_cast<const float4*>(scsh + kc + 4);
    float4 sha = *reinterpret_cast<const float4*>(scsh + CH + kc);
    float4 shb = *reinterpret_cast<const float4*>(scsh + CH + kc + 4);
    unsigned short h[8];
    h[0] = f2bf(fmaxf(fmaf(v0.x, sca.x, sha.x), 0.f));
    h[1] = f2bf(fmaxf(fmaf(v0.y, sca.y, sha.y), 0.f));
    h[2] = f2bf(fmaxf(fmaf(v0.z, sca.z, sha.z), 0.f));
    h[3] = f2bf(fmaxf(fmaf(v0.w, sca.w, sha.w), 0.f));
    h[4] = f2bf(fmaxf(fmaf(v1.x, scb.x, shb.x), 0.f));
    h[5] = f2bf(fmaxf(fmaf(v1.y, scb.y, shb.y), 0.f));
    h[6] = f2bf(fmaxf(fmaf(v1.z, scb.z, shb.z), 0.f));
    h[7] = f2bf(fmaxf(fmaf(v1.w, scb.w, shb.w), 0.f));
    int4 pk;
    pk.x = (int)h[0] | ((int)h[1] << 16);
    pk.y = (int)h[2] | ((int)h[3] << 16);
    pk.z = (int)h[4] | ((int)h[5] << 16);
    pk.w = (int)h[6] | ((int)h[7] << 16);
    int byte = (r * 256 + kc * 2) ^ ((r & 7) << 4);
    *reinterpret_cast<int4*>((char*)As + byte) = pk;
  }
  __syncthreads();

  const unsigned short* wt = Wt + ((size_t)wid << 14);
  const float* bias = wid == 0 ? bq_ : wid == 1 ? bk_ : wid == 2 ? bv_ : bs_;
  int lr = lane & 15;
  int lg = lane >> 4;

  f32x4 acc[4][8];
#pragma unroll
  for (int mt = 0; mt < 4; ++mt)
#pragma unroll
    for (int nt = 0; nt < 8; ++nt) acc[mt][nt] = (f32x4){0.f, 0.f, 0.f, 0.f};

  for (int ks = 0; ks < 4; ++ks) {
    bf16x8 a[4], b[8];
#pragma unroll
    for (int mt = 0; mt < 4; ++mt) {
      int r = mt * 16 + lr;
      int byte = (r * 256 + (ks * 32 + lg * 8) * 2) ^ ((r & 7) << 4);
      a[mt] = *reinterpret_cast<const bf16x8*>((const char*)As + byte);
    }
#pragma unroll
    for (int nt = 0; nt < 8; ++nt)
      b[nt] = *reinterpret_cast<const bf16x8*>(wt + (nt * 16 + lr) * 128 + ks * 32 + lg * 8);
    // swapped operands: D[ch][node] -> lane holds node=mt*16+lr, channels nt*16+lg*4+j
#pragma unroll
    for (int mt = 0; mt < 4; ++mt)
#pragma unroll
      for (int nt = 0; nt < 8; ++nt)
        acc[mt][nt] = __builtin_amdgcn_mfma_f32_16x16x32_bf16(b[nt], a[mt], acc[mt][nt], 0, 0, 0);
  }

  // all waves done reading As -> safe to reuse as per-wave staging (4KB each)
  __syncthreads();
  char* reg = (char*)As + wid * 4096;
  bool isfp8 = (wid == 1) || (wid == 2);
  unsigned short* o16 = (wid == 0) ? q : s_;
  unsigned char* o8 = (wid == 1) ? k8 : v8;

  if (!isfp8) {
#pragma unroll
    for (int mt = 0; mt < 4; ++mt) {
#pragma unroll
      for (int nt = 0; nt < 8; ++nt) {
        int cb = nt * 16 + lg * 4;
        float4 bb = *reinterpret_cast<const float4*>(bias + cb);
        ushort4 u;
        u.x = __builtin_bit_cast(unsigned short, (_Float16)(acc[mt][nt][0] + bb.x));
        u.y = __builtin_bit_cast(unsigned short, (_Float16)(acc[mt][nt][1] + bb.y));
        u.z = __builtin_bit_cast(unsigned short, (_Float16)(acc[mt][nt][2] + bb.z));
        u.w = __builtin_bit_cast(unsigned short, (_Float16)(acc[mt][nt][3] + bb.w));
        int byte = (lr * 256 + cb * 2) ^ ((lr & 7) << 4);
        *reinterpret_cast<ushort4*>(reg + byte) = u;
      }
#pragma unroll
      for (int i = 0; i < 4; ++i) {
        int r = i * 4 + (lane >> 4);
        int byte = (r * 256 + (lane & 15) * 16) ^ ((r & 7) << 4);
        int4 val = *reinterpret_cast<const int4*>(reg + byte);
        size_t row = row0 + mt * 16 + r;
        if (row < (size_t)N)
          *reinterpret_cast<int4*>(o16 + row * CH + (lane & 15) * 8) = val;
      }
    }
  } else {
#pragma unroll
    for (int mt = 0; mt < 4; ++mt) {
#pragma unroll
      for (int nt = 0; nt < 8; ++nt) {
        int cb = nt * 16 + lg * 4;
        float4 bb = *reinterpret_cast<const float4*>(bias + cb);
        unsigned int w = pkfp8<false>(acc[mt][nt][0] + bb.x, acc[mt][nt][1] + bb.y, 0u);
        w = pkfp8<true>(acc[mt][nt][2] + bb.z, acc[mt][nt][3] + bb.w, w);
        int byte = (lr * 128 + cb) ^ ((lr & 7) << 4);
        *reinterpret_cast<unsigned int*>(reg + byte) = w;
      }
#pragma unroll
      for (int i = 0; i < 2; ++i) {
        int r = i * 8 + (lane >> 3);
        int byte = (r * 128 + (lane & 7) * 16) ^ ((r & 7) << 4);
        int4 val = *reinterpret_cast<const int4*>(reg + byte);
        size_t row = row0 + mt * 16 + r;
        if (row < (size_t)N)
          *reinterpret_cast<int4*>(o8 + row * CH + (lane & 7) * 16) = val;
      }
    }
  }
}

// ---------- 3. fused CSR build: one pass, padded slots (no scan, no scatter) ----------
__global__ void deg_scatter_kernel(const int* __restrict__ src, const int* __restrict__ dst,
                                   int* __restrict__ deg, int* __restrict__ slots, int E) {
  for (int e = blockIdx.x * blockDim.x + threadIdx.x; e < E; e += gridDim.x * blockDim.x) {
    int d = dst[e];
    int r = atomicAdd(&deg[d], 1);
    if (r < SLOTS) slots[(size_t)d * SLOTS + r] = src[e];
  }
}

// ---------- 4. per-dst softmax (no max; range-safe) + aggregation; fp8 k/v ----------
// 1 wave per node (grid-stride). 8 edges per iteration (2 slots, loads up front).
// conv aliases q: q[n] fully consumed by the owning wave before conv[n] is written.
__global__ __launch_bounds__(256) void attn_kernel(
    const unsigned short* __restrict__ q, const unsigned char* __restrict__ k8,
    const unsigned char* __restrict__ v8, const unsigned short* __restrict__ skp,
    const int* __restrict__ deg, const int* __restrict__ slots,
    unsigned short* __restrict__ conv, int N, int nw) {
  int lane = threadIdx.x & 63;
  int g = lane >> 4;
  int s = lane & 15;
  int w0 = blockIdx.x * (blockDim.x >> 6) + (threadIdx.x >> 6);
  const float ASC = 0.17677669529663687f;  // 1/sqrt(32)
  for (int n = w0; n < N; n += nw) {
    int dg = deg[n];
    if (dg > SLOTS) dg = SLOTS;
    const int* sl = slots + (size_t)n * SLOTS;
    size_t rowb = (size_t)n * CH + s * 8;
    uint4 qr = *reinterpret_cast<const uint4*>(q + rowb);
    f32x2 qv[4];
    {
      f16x2 t0 = __builtin_bit_cast(f16x2, qr.x);
      f16x2 t1 = __builtin_bit_cast(f16x2, qr.y);
      f16x2 t2 = __builtin_bit_cast(f16x2, qr.z);
      f16x2 t3 = __builtin_bit_cast(f16x2, qr.w);
      qv[0] = (f32x2){(float)t0[0] * ASC, (float)t0[1] * ASC};
      qv[1] = (f32x2){(float)t1[0] * ASC, (float)t1[1] * ASC};
      qv[2] = (f32x2){(float)t2[0] * ASC, (float)t2[1] * ASC};
      qv[3] = (f32x2){(float)t3[0] * ASC, (float)t3[1] * ASC};
    }
    float ssum = 0.f;
    f32x2 vA = (f32x2){0.f, 0.f}, vB = vA, vC = vA, vD = vA;
    int nit2 = (dg + 7) >> 3;
    for (int it = 0; it < nit2; ++it) {
      int e0 = it * 8 + g;
      int e1 = e0 + 4;
      bool v0 = e0 < dg;
      bool v1 = e1 < dg;
      int src0 = sl[v0 ? e0 : 0];
      int src1 = sl[v1 ? e1 : 0];
      size_t sb0 = (size_t)src0 * CH + s * 8;
      size_t sb1 = (size_t)src1 * CH + s * 8;
      uint2 kr0 = *reinterpret_cast<const uint2*>(k8 + sb0);
      uint2 vr0 = *reinterpret_cast<const uint2*>(v8 + sb0);
      uint2 kr1 = *reinterpret_cast<const uint2*>(k8 + sb1);
      uint2 vr1 = *reinterpret_cast<const uint2*>(v8 + sb1);
      f32x2 p0 = upkfp8<false>(kr0.x) * qv[0];
      p0 += upkfp8<true>(kr0.x) * qv[1];
      p0 += upkfp8<false>(kr0.y) * qv[2];
      p0 += upkfp8<true>(kr0.y) * qv[3];
      float pa = p0[0] + p0[1];
      f32x2 p1 = upkfp8<false>(kr1.x) * qv[0];
      p1 += upkfp8<true>(kr1.x) * qv[1];
      p1 += upkfp8<false>(kr1.y) * qv[2];
      p1 += upkfp8<true>(kr1.y) * qv[3];
      float pb = p1[0] + p1[1];
      pa += __shfl_xor(pa, 1);
      pb += __shfl_xor(pb, 1);
      pa += __shfl_xor(pa, 2);
      pb += __shfl_xor(pb, 2);
      float ex0 = v0 ? __expf(pa) : 0.f;
      float ex1 = v1 ? __expf(pb) : 0.f;
      ssum += ex0 + ex1;
      f32x2 e20 = (f32x2){ex0, ex0};
      f32x2 e21 = (f32x2){ex1, ex1};
      vA += e20 * upkfp8<false>(vr0.x);
      vB += e20 * upkfp8<true>(vr0.x);
      vC += e20 * upkfp8<false>(vr0.y);
      vD += e20 * upkfp8<true>(vr0.y);
      vA += e21 * upkfp8<false>(vr1.x);
      vB += e21 * upkfp8<true>(vr1.x);
      vC += e21 * upkfp8<false>(vr1.y);
      vD += e21 * upkfp8<true>(vr1.y);
    }
    float va[8] = {vA[0], vA[1], vB[0], vB[1], vC[0], vC[1], vD[0], vD[1]};
#pragma unroll
    for (int msk = 16; msk <= 32; msk <<= 1) {
      ssum += __shfl_xor(ssum, msk);
#pragma unroll
      for (int i = 0; i < 8; ++i) va[i] += __shfl_xor(va[i], msk);
    }
    float inv = (dg > 0) ? 1.0f / ssum : 0.f;
    if (g == 0) {
      uint4 sr = *reinterpret_cast<const uint4*>(skp + rowb);
      f16x2 s0 = __builtin_bit_cast(f16x2, sr.x);
      f16x2 s1 = __builtin_bit_cast(f16x2, sr.y);
      f16x2 s2 = __builtin_bit_cast(f16x2, sr.z);
      f16x2 s3 = __builtin_bit_cast(f16x2, sr.w);
      int4 pk;
      pk.x = (int)f2bf(va[0] * inv + (float)s0[0]) | ((int)f2bf(va[1] * inv + (float)s0[1]) << 16);
      pk.y = (int)f2bf(va[2] * inv + (float)s1[0]) | ((int)f2bf(va[3] * inv + (float)s1[1]) << 16);
      pk.z = (int)f2bf(va[4] * inv + (float)s2[0]) | ((int)f2bf(va[5] * inv + (float)s2[1]) << 16);
      pk.w = (int)f2bf(va[6] * inv + (float)s3[0]) | ((int)f2bf(va[7] * inv + (float)s3[1]) << 16);
      *reinterpret_cast<int4*>(conv + rowb) = pk;
    }
  }
}

// ---------- 5. out = conv @ Wfc + bfc + x via MFMA; LDS-staged coalesced epilogue ----------
__global__ __launch_bounds__(256) void final_mfma_kernel(
    const unsigned short* __restrict__ conv, const unsigned short* __restrict__ Wt,
    const float* __restrict__ bfc, const float* __restrict__ x,
    float* __restrict__ outp, int N) {
  __shared__ __align__(16) unsigned short As[64 * 128];
  int t = threadIdx.x;
  int lane = t & 63;
  int wid = t >> 6;
  size_t row0 = (size_t)blockIdx.x * 64;

  for (int i = 0; i < 4; ++i) {
    int c = i * 256 + t;
    int r = c >> 4;
    int kc = (c & 15) * 8;
    int4 pk = make_int4(0, 0, 0, 0);
    if (row0 + r < (size_t)N)
      pk = *reinterpret_cast<const int4*>(conv + (row0 + r) * CH + kc);
    int byte = (r * 256 + kc * 2) ^ ((r & 7) << 4);
    *reinterpret_cast<int4*>((char*)As + byte) = pk;
  }
  __syncthreads();

  const unsigned short* wt = Wt + ((size_t)4 << 14);
  int lr = lane & 15;
  int lg = lane >> 4;

  f32x4 acc[4][2];
#pragma unroll
  for (int mt = 0; mt < 4; ++mt)
#pragma unroll
    for (int i = 0; i < 2; ++i) acc[mt][i] = (f32x4){0.f, 0.f, 0.f, 0.f};

  for (int ks = 0; ks < 4; ++ks) {
    bf16x8 a[4], b[2];
#pragma unroll
    for (int mt = 0; mt < 4; ++mt) {
      int r = mt * 16 + lr;
      int byte = (r * 256 + (ks * 32 + lg * 8) * 2) ^ ((r & 7) << 4);
      a[mt] = *reinterpret_cast<const bf16x8*>((const char*)As + byte);
    }
#pragma unroll
    for (int i = 0; i < 2; ++i) {
      int n = (wid * 2 + i) * 16 + lr;
      b[i] = *reinterpret_cast<const bf16x8*>(wt + n * 128 + ks * 32 + lg * 8);
    }
#pragma unroll
    for (int mt = 0; mt < 4; ++mt)
#pragma unroll
      for (int i = 0; i < 2; ++i)
        acc[mt][i] = __builtin_amdgcn_mfma_f32_16x16x32_bf16(b[i], a[mt], acc[mt][i], 0, 0, 0);
  }

  // stage f32 outputs through per-wave 4KB LDS -> full-line coalesced stores
  __syncthreads();
  char* reg = (char*)As + wid * 4096;
#pragma unroll
  for (int mt = 0; mt < 4; ++mt) {
#pragma unroll
    for (int i = 0; i < 2; ++i) {
      int byte = (lr * 128 + i * 64 + lg * 16) ^ ((lr & 7) << 4);
      *reinterpret_cast<f32x4*>(reg + byte) = acc[mt][i];
    }
#pragma unroll
    for (int i2 = 0; i2 < 2; ++i2) {
      int r = i2 * 8 + (lane >> 3);
      int byte = (r * 128 + (lane & 7) * 16) ^ ((r & 7) << 4);
      f32x4 val = *reinterpret_cast<const f32x4*>(reg + byte);
      int ch = wid * 32 + (lane & 7) * 4;
      size_t row = row0 + mt * 16 + r;
      if (row < (size_t)N) {
        float4 bb = *reinterpret_cast<const float4*>(bfc + ch);
        float4 rx = *reinterpret_cast<const float4*>(x + row * CH + ch);
        float4 o;
        o.x = val[0] + bb.x + rx.x;
        o.y = val[1] + bb.y + rx.y;
        o.z = val[2] + bb.z + rx.z;
        o.w = val[3] + bb.w + rx.w;
        *reinterpret_cast<float4*>(outp + row * CH + ch) = o;
      }
    }
  }
}

// ---------------------------------------------------------------
extern "C" void kernel_launch(void* const* d_in, const int* in_sizes, int n_in,
                              void* d_out, int out_size, void* d_ws, size_t ws_size,
                              hipStream_t stream) {
  const float* x = (const float*)d_in[0];
  const int* ei = (const int*)d_in[1];
  const float* gamma = (const float*)d_in[2];
  const float* beta = (const float*)d_in[3];
  const float* Wq = (const float*)d_in[4];
  const float* bq = (const float*)d_in[5];
  const float* Wk = (const float*)d_in[6];
  const float* bk = (const float*)d_in[7];
  const float* Wv = (const float*)d_in[8];
  const float* bv = (const float*)d_in[9];
  const float* Ws = (const float*)d_in[10];
  const float* bs = (const float*)d_in[11];
  const float* Wfc = (const float*)d_in[12];
  const float* bfc = (const float*)d_in[13];

  const int N = in_sizes[0] / CH;
  const int E = in_sizes[1] / 2;
  const int* srcp = ei;
  const int* dstp = ei + E;
  float* outp = (float*)d_out;

  char* wsb = (char*)d_ws;
  size_t off = 0;
  auto take = [&](size_t bytes) -> void* {
    void* p = wsb + off;
    off = (off + bytes + 255) & ~(size_t)255;
    return p;
  };
  float* stats = (float*)take(256 * 4);
  unsigned short* Wt = (unsigned short*)take((size_t)5 * 16384 * 2);
  unsigned short* qb = (unsigned short*)take((size_t)N * CH * 2);  // conv aliases this
  unsigned char* kb8 = (unsigned char*)take((size_t)N * CH);
  unsigned char* vb8 = (unsigned char*)take((size_t)N * CH);
  unsigned short* sb = (unsigned short*)take((size_t)N * CH * 2);
  int* deg = (int*)take((size_t)N * 4);
  int* slots = (int*)take((size_t)N * SLOTS * 4);
  unsigned short* convb = qb;  // alias: q consumed before conv written (same wave, same row)

  (void)hipMemsetAsync(stats, 0, 256 * 4, stream);
  (void)hipMemsetAsync(deg, 0, (size_t)N * 4, stream);

  bn_stats_kernel<<<512, 256, 0, stream>>>(x, stats, N);
  pack_w_kernel<<<320, 256, 0, stream>>>(Wq, Wk, Wv, Ws, Wfc, Wt);

  int nblk = (N + 63) / 64;
  proj_mfma_kernel<<<nblk, 256, 0, stream>>>(x, stats, gamma, beta, Wt, bq, bk, bv, bs, qb, kb8,
                                             vb8, sb, N);

  deg_scatter_kernel<<<2048, 256, 0, stream>>>(srcp, dstp, deg, slots, E);

  int ablocks = 4096;
  attn_kernel<<<ablocks, 256, 0, stream>>>(qb, kb8, vb8, sb, deg, slots, convb, N, ablocks * 4);
  final_mfma_kernel<<<nblk, 256, 0, stream>>>(convb, Wt, bfc, x, outp, N);
}

// Round 14
// 335.310 us; speedup vs baseline: 1.0209x; 1.0209x over previous
//
#include <hip/hip_runtime.h>

#define CH 128  // channels = H*D = 4*32
#define SLOTS 64  // padded per-node edge slots; P(deg>=64 | Poisson(16)) ~ 1e-19

typedef short bf16x8 __attribute__((ext_vector_type(8)));
typedef float f32x4 __attribute__((ext_vector_type(4)));
typedef float f32x2 __attribute__((ext_vector_type(2)));
typedef _Float16 f16x2 __attribute__((ext_vector_type(2)));

// ---------- helpers ----------
static __device__ __forceinline__ unsigned short f2bf(float f) {
  union { float f; unsigned int i; } c;
  c.f = f;
  unsigned int r = c.i + 0x7fffu + ((c.i >> 16) & 1u);  // RNE
  return (unsigned short)(r >> 16);
}

// fp8 e4m3 fallbacks (used only if builtins are missing)
static __device__ float fp82f_sw(unsigned int b) {
  int sgn = (b >> 7) & 1;
  int e = (b >> 3) & 15;
  int m = b & 7;
  float v = e ? ldexpf(1.f + m * 0.125f, e - 7) : ldexpf((float)m, -9);
  return sgn ? -v : v;
}
static __device__ unsigned char f2fp8_sw(float f) {
  unsigned char s = (f < 0.f) ? 0x80 : 0;
  float af = fabsf(f);
  if (!(af < 448.f)) return s | 0x7e;
  int ex;
  frexpf(af, &ex);
  int e = ex - 1;
  if (e < -6) e = -6;
  float step = ldexpf(1.f, e - 3);
  float qq = rintf(af / step);
  if (qq >= 16.f) { qq = 8.f; e += 1; }
  if (e > 8) return s | 0x7e;
  unsigned char bits = (qq < 8.f) ? (unsigned char)qq
                                  : (unsigned char)(((e + 7) << 3) | ((int)qq - 8));
  return s | bits;
}
template <bool HI>
static __device__ __forceinline__ unsigned int pkfp8(float a, float b, unsigned int old) {
#if __has_builtin(__builtin_amdgcn_cvt_pk_fp8_f32)
  return (unsigned int)__builtin_amdgcn_cvt_pk_fp8_f32(a, b, (int)old, HI);
#else
  unsigned int w = ((unsigned)f2fp8_sw(a)) | (((unsigned)f2fp8_sw(b)) << 8);
  return HI ? ((old & 0x0000ffffu) | (w << 16)) : ((old & 0xffff0000u) | w);
#endif
}
template <bool HI>
static __device__ __forceinline__ f32x2 upkfp8(unsigned int src) {
#if __has_builtin(__builtin_amdgcn_cvt_pk_f32_fp8)
  return __builtin_amdgcn_cvt_pk_f32_fp8((int)src, HI);
#else
  unsigned int h = HI ? (src >> 16) : (src & 0xffffu);
  f32x2 r;
  r[0] = fp82f_sw(h & 0xff);
  r[1] = fp82f_sw((h >> 8) & 0xff);
  return r;
#endif
}

// ---------- 1. BatchNorm statistics ----------
__global__ void bn_stats_kernel(const float* __restrict__ x, float* __restrict__ stats, int N) {
  int t = threadIdx.x;
  int ch = t & (CH - 1);
  int r0 = t >> 7;
  float s = 0.f, ss = 0.f;
  for (int row = blockIdx.x * 2 + r0; row < N; row += gridDim.x * 2) {
    float v = x[(size_t)row * CH + ch];
    s += v;
    ss += v * v;
  }
  atomicAdd(&stats[ch], s);
  atomicAdd(&stats[CH + ch], ss);
}

// ---------- 1b. pack weights: Wt[mat][n][k] bf16, mats = q,k,v,skip,fc ----------
__global__ void pack_w_kernel(const float* __restrict__ Wq, const float* __restrict__ Wk,
                              const float* __restrict__ Wv, const float* __restrict__ Ws,
                              const float* __restrict__ Wfc, unsigned short* __restrict__ Wt) {
  int el = blockIdx.x * 256 + threadIdx.x;  // 5*16384 elements
  int mat = el >> 14;
  int rem = el & 16383;
  int kk = rem >> 7;
  int n = rem & 127;
  const float* W = mat == 0 ? Wq : mat == 1 ? Wk : mat == 2 ? Wv : mat == 3 ? Ws : Wfc;
  Wt[((size_t)mat << 14) + n * 128 + kk] = f2bf(W[kk * 128 + n]);
}

// ---------- 2. fused BN+ReLU + 4 projections via MFMA ----------
// BN scale/shift derived per-block from stats. Swapped-operand MFMA; epilogue
// staged through per-wave 4KB LDS region -> full-cache-line coalesced stores.
// wave 0 -> q (f16), wave 1 -> k (fp8), wave 2 -> v (fp8), wave 3 -> skip (f16)
__global__ __launch_bounds__(256, 2) void proj_mfma_kernel(
    const float* __restrict__ x, const float* __restrict__ stats,
    const float* __restrict__ gamma, const float* __restrict__ beta,
    const unsigned short* __restrict__ Wt,
    const float* __restrict__ bq_, const float* __restrict__ bk_,
    const float* __restrict__ bv_, const float* __restrict__ bs_,
    unsigned short* __restrict__ q, unsigned char* __restrict__ k8,
    unsigned char* __restrict__ v8, unsigned short* __restrict__ s_, int N) {
  __shared__ __align__(16) unsigned short As[64 * 128];  // 16KB, XOR-swizzled
  __shared__ __align__(16) float scsh[256];
  int t = threadIdx.x;
  int lane = t & 63;
  int wid = t >> 6;
  size_t row0 = (size_t)blockIdx.x * 64;

  if (t < CH) {
    float inv_n = 1.0f / (float)N;
    float mu = stats[t] * inv_n;
    float var = stats[CH + t] * inv_n - mu * mu;
    float sc = gamma[t] * rsqrtf(var + 1e-5f);
    scsh[t] = sc;
    scsh[CH + t] = beta[t] - mu * sc;
  }
  __syncthreads();

  for (int i = 0; i < 4; ++i) {
    int c = i * 256 + t;
    int r = c >> 4;
    int kc = (c & 15) * 8;
    float4 v0 = make_float4(0.f, 0.f, 0.f, 0.f), v1 = v0;
    if (row0 + r < (size_t)N) {
      const float* g = x + (row0 + r) * CH + kc;
      v0 = *reinterpret_cast<const float4*>(g);
      v1 = *reinterpret_cast<const float4*>(g + 4);
    }
    float4 sca = *reinterpret_cast<const float4*>(scsh + kc);
    float4 scb = *reinterpret_cast<const float4*>(scsh + kc + 4);
    float4 sha = *reinterpret_cast<const float4*>(scsh + CH + kc);
    float4 shb = *reinterpret_cast<const float4*>(scsh + CH + kc + 4);
    unsigned short h[8];
    h[0] = f2bf(fmaxf(fmaf(v0.x, sca.x, sha.x), 0.f));
    h[1] = f2bf(fmaxf(fmaf(v0.y, sca.y, sha.y), 0.f));
    h[2] = f2bf(fmaxf(fmaf(v0.z, sca.z, sha.z), 0.f));
    h[3] = f2bf(fmaxf(fmaf(v0.w, sca.w, sha.w), 0.f));
    h[4] = f2bf(fmaxf(fmaf(v1.x, scb.x, shb.x), 0.f));
    h[5] = f2bf(fmaxf(fmaf(v1.y, scb.y, shb.y), 0.f));
    h[6] = f2bf(fmaxf(fmaf(v1.z, scb.z, shb.z), 0.f));
    h[7] = f2bf(fmaxf(fmaf(v1.w, scb.w, shb.w), 0.f));
    int4 pk;
    pk.x = (int)h[0] | ((int)h[1] << 16);
    pk.y = (int)h[2] | ((int)h[3] << 16);
    pk.z = (int)h[4] | ((int)h[5] << 16);
    pk.w = (int)h[6] | ((int)h[7] << 16);
    int byte = (r * 256 + kc * 2) ^ ((r & 7) << 4);
    *reinterpret_cast<int4*>((char*)As + byte) = pk;
  }
  __syncthreads();

  const unsigned short* wt = Wt + ((size_t)wid << 14);
  const float* bias = wid == 0 ? bq_ : wid == 1 ? bk_ : wid == 2 ? bv_ : bs_;
  int lr = lane & 15;
  int lg = lane >> 4;

  f32x4 acc[4][8];
#pragma unroll
  for (int mt = 0; mt < 4; ++mt)
#pragma unroll
    for (int nt = 0; nt < 8; ++nt) acc[mt][nt] = (f32x4){0.f, 0.f, 0.f, 0.f};

  for (int ks = 0; ks < 4; ++ks) {
    bf16x8 a[4], b[8];
#pragma unroll
    for (int mt = 0; mt < 4; ++mt) {
      int r = mt * 16 + lr;
      int byte = (r * 256 + (ks * 32 + lg * 8) * 2) ^ ((r & 7) << 4);
      a[mt] = *reinterpret_cast<const bf16x8*>((const char*)As + byte);
    }
#pragma unroll
    for (int nt = 0; nt < 8; ++nt)
      b[nt] = *reinterpret_cast<const bf16x8*>(wt + (nt * 16 + lr) * 128 + ks * 32 + lg * 8);
    // swapped operands: D[ch][node] -> lane holds node=mt*16+lr, channels nt*16+lg*4+j
#pragma unroll
    for (int mt = 0; mt < 4; ++mt)
#pragma unroll
      for (int nt = 0; nt < 8; ++nt)
        acc[mt][nt] = __builtin_amdgcn_mfma_f32_16x16x32_bf16(b[nt], a[mt], acc[mt][nt], 0, 0, 0);
  }

  // all waves done reading As -> safe to reuse as per-wave staging (4KB each)
  __syncthreads();
  char* reg = (char*)As + wid * 4096;
  bool isfp8 = (wid == 1) || (wid == 2);
  unsigned short* o16 = (wid == 0) ? q : s_;
  unsigned char* o8 = (wid == 1) ? k8 : v8;

  if (!isfp8) {
#pragma unroll
    for (int mt = 0; mt < 4; ++mt) {
#pragma unroll
      for (int nt = 0; nt < 8; ++nt) {
        int cb = nt * 16 + lg * 4;
        float4 bb = *reinterpret_cast<const float4*>(bias + cb);
        ushort4 u;
        u.x = __builtin_bit_cast(unsigned short, (_Float16)(acc[mt][nt][0] + bb.x));
        u.y = __builtin_bit_cast(unsigned short, (_Float16)(acc[mt][nt][1] + bb.y));
        u.z = __builtin_bit_cast(unsigned short, (_Float16)(acc[mt][nt][2] + bb.z));
        u.w = __builtin_bit_cast(unsigned short, (_Float16)(acc[mt][nt][3] + bb.w));
        int byte = (lr * 256 + cb * 2) ^ ((lr & 7) << 4);
        *reinterpret_cast<ushort4*>(reg + byte) = u;
      }
#pragma unroll
      for (int i = 0; i < 4; ++i) {
        int r = i * 4 + (lane >> 4);
        int byte = (r * 256 + (lane & 15) * 16) ^ ((r & 7) << 4);
        int4 val = *reinterpret_cast<const int4*>(reg + byte);
        size_t row = row0 + mt * 16 + r;
        if (row < (size_t)N)
          *reinterpret_cast<int4*>(o16 + row * CH + (lane & 15) * 8) = val;
      }
    }
  } else {
#pragma unroll
    for (int mt = 0; mt < 4; ++mt) {
#pragma unroll
      for (int nt = 0; nt < 8; ++nt) {
        int cb = nt * 16 + lg * 4;
        float4 bb = *reinterpret_cast<const float4*>(bias + cb);
        unsigned int w = pkfp8<false>(acc[mt][nt][0] + bb.x, acc[mt][nt][1] + bb.y, 0u);
        w = pkfp8<true>(acc[mt][nt][2] + bb.z, acc[mt][nt][3] + bb.w, w);
        int byte = (lr * 128 + cb) ^ ((lr & 7) << 4);
        *reinterpret_cast<unsigned int*>(reg + byte) = w;
      }
#pragma unroll
      for (int i = 0; i < 2; ++i) {
        int r = i * 8 + (lane >> 3);
        int byte = (r * 128 + (lane & 7) * 16) ^ ((r & 7) << 4);
        int4 val = *reinterpret_cast<const int4*>(reg + byte);
        size_t row = row0 + mt * 16 + r;
        if (row < (size_t)N)
          *reinterpret_cast<int4*>(o8 + row * CH + (lane & 7) * 16) = val;
      }
    }
  }
}

// ---------- 3. fused CSR build: one pass, padded slots (no scan, no scatter) ----------
__global__ void deg_scatter_kernel(const int* __restrict__ src, const int* __restrict__ dst,
                                   int* __restrict__ deg, int* __restrict__ slots, int E) {
  for (int e = blockIdx.x * blockDim.x + threadIdx.x; e < E; e += gridDim.x * blockDim.x) {
    int d = dst[e];
    int r = atomicAdd(&deg[d], 1);
    if (r < SLOTS) slots[(size_t)d * SLOTS + r] = src[e];
  }
}

// ---------- 4. per-dst softmax (no max; range-safe) + aggregation; fp8 k/v ----------
// 1 wave per node (grid-stride). 8 edges per iteration (2 slots, loads up front).
// conv aliases q: q[n] fully consumed by the owning wave before conv[n] is written.
__global__ __launch_bounds__(256) void attn_kernel(
    const unsigned short* __restrict__ q, const unsigned char* __restrict__ k8,
    const unsigned char* __restrict__ v8, const unsigned short* __restrict__ skp,
    const int* __restrict__ deg, const int* __restrict__ slots,
    unsigned short* __restrict__ conv, int N, int nw) {
  int lane = threadIdx.x & 63;
  int g = lane >> 4;
  int s = lane & 15;
  int w0 = blockIdx.x * (blockDim.x >> 6) + (threadIdx.x >> 6);
  const float ASC = 0.17677669529663687f;  // 1/sqrt(32)
  for (int n = w0; n < N; n += nw) {
    int dg = deg[n];
    if (dg > SLOTS) dg = SLOTS;
    const int* sl = slots + (size_t)n * SLOTS;
    size_t rowb = (size_t)n * CH + s * 8;
    uint4 qr = *reinterpret_cast<const uint4*>(q + rowb);
    f32x2 qv[4];
    {
      f16x2 t0 = __builtin_bit_cast(f16x2, qr.x);
      f16x2 t1 = __builtin_bit_cast(f16x2, qr.y);
      f16x2 t2 = __builtin_bit_cast(f16x2, qr.z);
      f16x2 t3 = __builtin_bit_cast(f16x2, qr.w);
      qv[0] = (f32x2){(float)t0[0] * ASC, (float)t0[1] * ASC};
      qv[1] = (f32x2){(float)t1[0] * ASC, (float)t1[1] * ASC};
      qv[2] = (f32x2){(float)t2[0] * ASC, (float)t2[1] * ASC};
      qv[3] = (f32x2){(float)t3[0] * ASC, (float)t3[1] * ASC};
    }
    float ssum = 0.f;
    f32x2 vA = (f32x2){0.f, 0.f}, vB = vA, vC = vA, vD = vA;
    int nit2 = (dg + 7) >> 3;
    for (int it = 0; it < nit2; ++it) {
      int e0 = it * 8 + g;
      int e1 = e0 + 4;
      bool v0 = e0 < dg;
      bool v1 = e1 < dg;
      int src0 = sl[v0 ? e0 : 0];
      int src1 = sl[v1 ? e1 : 0];
      size_t sb0 = (size_t)src0 * CH + s * 8;
      size_t sb1 = (size_t)src1 * CH + s * 8;
      uint2 kr0 = *reinterpret_cast<const uint2*>(k8 + sb0);
      uint2 vr0 = *reinterpret_cast<const uint2*>(v8 + sb0);
      uint2 kr1 = *reinterpret_cast<const uint2*>(k8 + sb1);
      uint2 vr1 = *reinterpret_cast<const uint2*>(v8 + sb1);
      f32x2 p0 = upkfp8<false>(kr0.x) * qv[0];
      p0 += upkfp8<true>(kr0.x) * qv[1];
      p0 += upkfp8<false>(kr0.y) * qv[2];
      p0 += upkfp8<true>(kr0.y) * qv[3];
      float pa = p0[0] + p0[1];
      f32x2 p1 = upkfp8<false>(kr1.x) * qv[0];
      p1 += upkfp8<true>(kr1.x) * qv[1];
      p1 += upkfp8<false>(kr1.y) * qv[2];
      p1 += upkfp8<true>(kr1.y) * qv[3];
      float pb = p1[0] + p1[1];
      pa += __shfl_xor(pa, 1);
      pb += __shfl_xor(pb, 1);
      pa += __shfl_xor(pa, 2);
      pb += __shfl_xor(pb, 2);
      float ex0 = v0 ? __expf(pa) : 0.f;
      float ex1 = v1 ? __expf(pb) : 0.f;
      ssum += ex0 + ex1;
      f32x2 e20 = (f32x2){ex0, ex0};
      f32x2 e21 = (f32x2){ex1, ex1};
      vA += e20 * upkfp8<false>(vr0.x);
      vB += e20 * upkfp8<true>(vr0.x);
      vC += e20 * upkfp8<false>(vr0.y);
      vD += e20 * upkfp8<true>(vr0.y);
      vA += e21 * upkfp8<false>(vr1.x);
      vB += e21 * upkfp8<true>(vr1.x);
      vC += e21 * upkfp8<false>(vr1.y);
      vD += e21 * upkfp8<true>(vr1.y);
    }
    float va[8] = {vA[0], vA[1], vB[0], vB[1], vC[0], vC[1], vD[0], vD[1]};
#pragma unroll
    for (int msk = 16; msk <= 32; msk <<= 1) {
      ssum += __shfl_xor(ssum, msk);
#pragma unroll
      for (int i = 0; i < 8; ++i) va[i] += __shfl_xor(va[i], msk);
    }
    float inv = (dg > 0) ? 1.0f / ssum : 0.f;
    if (g == 0) {
      uint4 sr = *reinterpret_cast<const uint4*>(skp + rowb);
      f16x2 s0 = __builtin_bit_cast(f16x2, sr.x);
      f16x2 s1 = __builtin_bit_cast(f16x2, sr.y);
      f16x2 s2 = __builtin_bit_cast(f16x2, sr.z);
      f16x2 s3 = __builtin_bit_cast(f16x2, sr.w);
      int4 pk;
      pk.x = (int)f2bf(va[0] * inv + (float)s0[0]) | ((int)f2bf(va[1] * inv + (float)s0[1]) << 16);
      pk.y = (int)f2bf(va[2] * inv + (float)s1[0]) | ((int)f2bf(va[3] * inv + (float)s1[1]) << 16);
      pk.z = (int)f2bf(va[4] * inv + (float)s2[0]) | ((int)f2bf(va[5] * inv + (float)s2[1]) << 16);
      pk.w = (int)f2bf(va[6] * inv + (float)s3[0]) | ((int)f2bf(va[7] * inv + (float)s3[1]) << 16);
      *reinterpret_cast<int4*>(conv + rowb) = pk;
    }
  }
}

// ---------- 5. out = conv @ Wfc + bfc + x via MFMA; LDS-staged coalesced epilogue ----------
__global__ __launch_bounds__(256) void final_mfma_kernel(
    const unsigned short* __restrict__ conv, const unsigned short* __restrict__ Wt,
    const float* __restrict__ bfc, const float* __restrict__ x,
    float* __restrict__ outp, int N) {
  __shared__ __align__(16) unsigned short As[64 * 128];
  int t = threadIdx.x;
  int lane = t & 63;
  int wid = t >> 6;
  size_t row0 = (size_t)blockIdx.x * 64;

  for (int i = 0; i < 4; ++i) {
    int c = i * 256 + t;
    int r = c >> 4;
    int kc = (c & 15) * 8;
    int4 pk = make_int4(0, 0, 0, 0);
    if (row0 + r < (size_t)N)
      pk = *reinterpret_cast<const int4*>(conv + (row0 + r) * CH + kc);
    int byte = (r * 256 + kc * 2) ^ ((r & 7) << 4);
    *reinterpret_cast<int4*>((char*)As + byte) = pk;
  }
  __syncthreads();

  const unsigned short* wt = Wt + ((size_t)4 << 14);
  int lr = lane & 15;
  int lg = lane >> 4;

  f32x4 acc[4][2];
#pragma unroll
  for (int mt = 0; mt < 4; ++mt)
#pragma unroll
    for (int i = 0; i < 2; ++i) acc[mt][i] = (f32x4){0.f, 0.f, 0.f, 0.f};

  for (int ks = 0; ks < 4; ++ks) {
    bf16x8 a[4], b[2];
#pragma unroll
    for (int mt = 0; mt < 4; ++mt) {
      int r = mt * 16 + lr;
      int byte = (r * 256 + (ks * 32 + lg * 8) * 2) ^ ((r & 7) << 4);
      a[mt] = *reinterpret_cast<const bf16x8*>((const char*)As + byte);
    }
#pragma unroll
    for (int i = 0; i < 2; ++i) {
      int n = (wid * 2 + i) * 16 + lr;
      b[i] = *reinterpret_cast<const bf16x8*>(wt + n * 128 + ks * 32 + lg * 8);
    }
#pragma unroll
    for (int mt = 0; mt < 4; ++mt)
#pragma unroll
      for (int i = 0; i < 2; ++i)
        acc[mt][i] = __builtin_amdgcn_mfma_f32_16x16x32_bf16(b[i], a[mt], acc[mt][i], 0, 0, 0);
  }

  // stage f32 outputs through per-wave 4KB LDS -> full-line coalesced stores
  __syncthreads();
  char* reg = (char*)As + wid * 4096;
#pragma unroll
  for (int mt = 0; mt < 4; ++mt) {
#pragma unroll
    for (int i = 0; i < 2; ++i) {
      int byte = (lr * 128 + i * 64 + lg * 16) ^ ((lr & 7) << 4);
      *reinterpret_cast<f32x4*>(reg + byte) = acc[mt][i];
    }
#pragma unroll
    for (int i2 = 0; i2 < 2; ++i2) {
      int r = i2 * 8 + (lane >> 3);
      int byte = (r * 128 + (lane & 7) * 16) ^ ((r & 7) << 4);
      f32x4 val = *reinterpret_cast<const f32x4*>(reg + byte);
      int ch = wid * 32 + (lane & 7) * 4;
      size_t row = row0 + mt * 16 + r;
      if (row < (size_t)N) {
        float4 bb = *reinterpret_cast<const float4*>(bfc + ch);
        float4 rx = *reinterpret_cast<const float4*>(x + row * CH + ch);
        float4 o;
        o.x = val[0] + bb.x + rx.x;
        o.y = val[1] + bb.y + rx.y;
        o.z = val[2] + bb.z + rx.z;
        o.w = val[3] + bb.w + rx.w;
        *reinterpret_cast<float4*>(outp + row * CH + ch) = o;
      }
    }
  }
}

// ---------------------------------------------------------------
extern "C" void kernel_launch(void* const* d_in, const int* in_sizes, int n_in,
                              void* d_out, int out_size, void* d_ws, size_t ws_size,
                              hipStream_t stream) {
  const float* x = (const float*)d_in[0];
  const int* ei = (const int*)d_in[1];
  const float* gamma = (const float*)d_in[2];
  const float* beta = (const float*)d_in[3];
  const float* Wq = (const float*)d_in[4];
  const float* bq = (const float*)d_in[5];
  const float* Wk = (const float*)d_in[6];
  const float* bk = (const float*)d_in[7];
  const float* Wv = (const float*)d_in[8];
  const float* bv = (const float*)d_in[9];
  const float* Ws = (const float*)d_in[10];
  const float* bs = (const float*)d_in[11];
  const float* Wfc = (const float*)d_in[12];
  const float* bfc = (const float*)d_in[13];

  const int N = in_sizes[0] / CH;
  const int E = in_sizes[1] / 2;
  const int* srcp = ei;
  const int* dstp = ei + E;
  float* outp = (float*)d_out;

  char* wsb = (char*)d_ws;
  size_t off = 0;
  auto take = [&](size_t bytes) -> void* {
    void* p = wsb + off;
    off = (off + bytes + 255) & ~(size_t)255;
    return p;
  };
  float* stats = (float*)take(256 * 4);
  unsigned short* Wt = (unsigned short*)take((size_t)5 * 16384 * 2);
  unsigned short* qb = (unsigned short*)take((size_t)N * CH * 2);  // conv aliases this
  unsigned char* kb8 = (unsigned char*)take((size_t)N * CH);
  unsigned char* vb8 = (unsigned char*)take((size_t)N * CH);
  unsigned short* sb = (unsigned short*)take((size_t)N * CH * 2);
  int* deg = (int*)take((size_t)N * 4);
  int* slots = (int*)take((size_t)N * SLOTS * 4);
  unsigned short* convb = qb;  // alias: q consumed before conv written (same wave, same row)

  (void)hipMemsetAsync(stats, 0, 256 * 4, stream);
  (void)hipMemsetAsync(deg, 0, (size_t)N * 4, stream);

  bn_stats_kernel<<<512, 256, 0, stream>>>(x, stats, N);
  pack_w_kernel<<<320, 256, 0, stream>>>(Wq, Wk, Wv, Ws, Wfc, Wt);

  int nblk = (N + 63) / 64;
  proj_mfma_kernel<<<nblk, 256, 0, stream>>>(x, stats, gamma, beta, Wt, bq, bk, bv, bs, qb, kb8,
                                             vb8, sb, N);

  deg_scatter_kernel<<<2048, 256, 0, stream>>>(srcp, dstp, deg, slots, E);

  int ablocks = 4096;
  attn_kernel<<<ablocks, 256, 0, stream>>>(qb, kb8, vb8, sb, deg, slots, convb, N, ablocks * 4);
  final_mfma_kernel<<<nblk, 256, 0, stream>>>(convb, Wt, bfc, x, outp, N);
}

// Round 15
// 304.995 us; speedup vs baseline: 1.1223x; 1.0994x over previous
//
#include <hip/hip_runtime.h>

#define CH 128  // channels = H*D = 4*32

typedef short bf16x8 __attribute__((ext_vector_type(8)));
typedef float f32x4 __attribute__((ext_vector_type(4)));
typedef float f32x2 __attribute__((ext_vector_type(2)));
typedef _Float16 f16x2 __attribute__((ext_vector_type(2)));

// ---------- helpers ----------
static __device__ __forceinline__ unsigned short f2bf(float f) {
  union { float f; unsigned int i; } c;
  c.f = f;
  unsigned int r = c.i + 0x7fffu + ((c.i >> 16) & 1u);  // RNE
  return (unsigned short)(r >> 16);
}

// fp8 e4m3 fallbacks (used only if builtins are missing)
static __device__ float fp82f_sw(unsigned int b) {
  int sgn = (b >> 7) & 1;
  int e = (b >> 3) & 15;
  int m = b & 7;
  float v = e ? ldexpf(1.f + m * 0.125f, e - 7) : ldexpf((float)m, -9);
  return sgn ? -v : v;
}
static __device__ unsigned char f2fp8_sw(float f) {
  unsigned char s = (f < 0.f) ? 0x80 : 0;
  float af = fabsf(f);
  if (!(af < 448.f)) return s | 0x7e;
  int ex;
  frexpf(af, &ex);
  int e = ex - 1;
  if (e < -6) e = -6;
  float step = ldexpf(1.f, e - 3);
  float qq = rintf(af / step);
  if (qq >= 16.f) { qq = 8.f; e += 1; }
  if (e > 8) return s | 0x7e;
  unsigned char bits = (qq < 8.f) ? (unsigned char)qq
                                  : (unsigned char)(((e + 7) << 3) | ((int)qq - 8));
  return s | bits;
}
template <bool HI>
static __device__ __forceinline__ unsigned int pkfp8(float a, float b, unsigned int old) {
#if __has_builtin(__builtin_amdgcn_cvt_pk_fp8_f32)
  return (unsigned int)__builtin_amdgcn_cvt_pk_fp8_f32(a, b, (int)old, HI);
#else
  unsigned int w = ((unsigned)f2fp8_sw(a)) | (((unsigned)f2fp8_sw(b)) << 8);
  return HI ? ((old & 0x0000ffffu) | (w << 16)) : ((old & 0xffff0000u) | w);
#endif
}
template <bool HI>
static __device__ __forceinline__ f32x2 upkfp8(unsigned int src) {
#if __has_builtin(__builtin_amdgcn_cvt_pk_f32_fp8)
  return __builtin_amdgcn_cvt_pk_f32_fp8((int)src, HI);
#else
  unsigned int h = HI ? (src >> 16) : (src & 0xffffu);
  f32x2 r;
  r[0] = fp82f_sw(h & 0xff);
  r[1] = fp82f_sw((h >> 8) & 0xff);
  return r;
#endif
}

// ---------- 1. BatchNorm statistics ----------
__global__ void bn_stats_kernel(const float* __restrict__ x, float* __restrict__ stats, int N) {
  int t = threadIdx.x;
  int ch = t & (CH - 1);
  int r0 = t >> 7;
  float s = 0.f, ss = 0.f;
  for (int row = blockIdx.x * 2 + r0; row < N; row += gridDim.x * 2) {
    float v = x[(size_t)row * CH + ch];
    s += v;
    ss += v * v;
  }
  atomicAdd(&stats[ch], s);
  atomicAdd(&stats[CH + ch], ss);
}

// ---------- 1b. pack weights: Wt[mat][n][k] bf16, mats = q,k,v,skip,fc ----------
__global__ void pack_w_kernel(const float* __restrict__ Wq, const float* __restrict__ Wk,
                              const float* __restrict__ Wv, const float* __restrict__ Ws,
                              const float* __restrict__ Wfc, unsigned short* __restrict__ Wt) {
  int el = blockIdx.x * 256 + threadIdx.x;  // 5*16384 elements
  int mat = el >> 14;
  int rem = el & 16383;
  int kk = rem >> 7;
  int n = rem & 127;
  const float* W = mat == 0 ? Wq : mat == 1 ? Wk : mat == 2 ? Wv : mat == 3 ? Ws : Wfc;
  Wt[((size_t)mat << 14) + n * 128 + kk] = f2bf(W[kk * 128 + n]);
}

// ---------- 2. fused BN+ReLU + 4 projections via MFMA ----------
// BN scale/shift derived per-block from stats. Swapped-operand MFMA; epilogue
// staged through per-wave 4KB LDS region -> full-cache-line coalesced stores.
// wave 0 -> q (f16), wave 1 -> k (fp8), wave 2 -> v (fp8), wave 3 -> skip (f16)
__global__ __launch_bounds__(256, 2) void proj_mfma_kernel(
    const float* __restrict__ x, const float* __restrict__ stats,
    const float* __restrict__ gamma, const float* __restrict__ beta,
    const unsigned short* __restrict__ Wt,
    const float* __restrict__ bq_, const float* __restrict__ bk_,
    const float* __restrict__ bv_, const float* __restrict__ bs_,
    unsigned short* __restrict__ q, unsigned char* __restrict__ k8,
    unsigned char* __restrict__ v8, unsigned short* __restrict__ s_, int N) {
  __shared__ __align__(16) unsigned short As[64 * 128];  // 16KB, XOR-swizzled
  __shared__ __align__(16) float scsh[256];
  int t = threadIdx.x;
  int lane = t & 63;
  int wid = t >> 6;
  size_t row0 = (size_t)blockIdx.x * 64;

  if (t < CH) {
    float inv_n = 1.0f / (float)N;
    float mu = stats[t] * inv_n;
    float var = stats[CH + t] * inv_n - mu * mu;
    float sc = gamma[t] * rsqrtf(var + 1e-5f);
    scsh[t] = sc;
    scsh[CH + t] = beta[t] - mu * sc;
  }
  __syncthreads();

  for (int i = 0; i < 4; ++i) {
    int c = i * 256 + t;
    int r = c >> 4;
    int kc = (c & 15) * 8;
    float4 v0 = make_float4(0.f, 0.f, 0.f, 0.f), v1 = v0;
    if (row0 + r < (size_t)N) {
      const float* g = x + (row0 + r) * CH + kc;
      v0 = *reinterpret_cast<const float4*>(g);
      v1 = *reinterpret_cast<const float4*>(g + 4);
    }
    float4 sca = *reinterpret_cast<const float4*>(scsh + kc);
    float4 scb = *reinterpret_cast<const float4*>(scsh + kc + 4);
    float4 sha = *reinterpret_cast<const float4*>(scsh + CH + kc);
    float4 shb = *reinterpret_cast<const float4*>(scsh + CH + kc + 4);
    unsigned short h[8];
    h[0] = f2bf(fmaxf(fmaf(v0.x, sca.x, sha.x), 0.f));
    h[1] = f2bf(fmaxf(fmaf(v0.y, sca.y, sha.y), 0.f));
    h[2] = f2bf(fmaxf(fmaf(v0.z, sca.z, sha.z), 0.f));
    h[3] = f2bf(fmaxf(fmaf(v0.w, sca.w, sha.w), 0.f));
    h[4] = f2bf(fmaxf(fmaf(v1.x, scb.x, shb.x), 0.f));
    h[5] = f2bf(fmaxf(fmaf(v1.y, scb.y, shb.y), 0.f));
    h[6] = f2bf(fmaxf(fmaf(v1.z, scb.z, shb.z), 0.f));
    h[7] = f2bf(fmaxf(fmaf(v1.w, scb.w, shb.w), 0.f));
    int4 pk;
    pk.x = (int)h[0] | ((int)h[1] << 16);
    pk.y = (int)h[2] | ((int)h[3] << 16);
    pk.z = (int)h[4] | ((int)h[5] << 16);
    pk.w = (int)h[6] | ((int)h[7] << 16);
    int byte = (r * 256 + kc * 2) ^ ((r & 7) << 4);
    *reinterpret_cast<int4*>((char*)As + byte) = pk;
  }
  __syncthreads();

  const unsigned short* wt = Wt + ((size_t)wid << 14);
  const float* bias = wid == 0 ? bq_ : wid == 1 ? bk_ : wid == 2 ? bv_ : bs_;
  int lr = lane & 15;
  int lg = lane >> 4;

  f32x4 acc[4][8];
#pragma unroll
  for (int mt = 0; mt < 4; ++mt)
#pragma unroll
    for (int nt = 0; nt < 8; ++nt) acc[mt][nt] = (f32x4){0.f, 0.f, 0.f, 0.f};

  for (int ks = 0; ks < 4; ++ks) {
    bf16x8 a[4], b[8];
#pragma unroll
    for (int mt = 0; mt < 4; ++mt) {
      int r = mt * 16 + lr;
      int byte = (r * 256 + (ks * 32 + lg * 8) * 2) ^ ((r & 7) << 4);
      a[mt] = *reinterpret_cast<const bf16x8*>((const char*)As + byte);
    }
#pragma unroll
    for (int nt = 0; nt < 8; ++nt)
      b[nt] = *reinterpret_cast<const bf16x8*>(wt + (nt * 16 + lr) * 128 + ks * 32 + lg * 8);
    // swapped operands: D[ch][node] -> lane holds node=mt*16+lr, channels nt*16+lg*4+j
#pragma unroll
    for (int mt = 0; mt < 4; ++mt)
#pragma unroll
      for (int nt = 0; nt < 8; ++nt)
        acc[mt][nt] = __builtin_amdgcn_mfma_f32_16x16x32_bf16(b[nt], a[mt], acc[mt][nt], 0, 0, 0);
  }

  // all waves done reading As -> safe to reuse as per-wave staging (4KB each)
  __syncthreads();
  char* reg = (char*)As + wid * 4096;
  bool isfp8 = (wid == 1) || (wid == 2);
  unsigned short* o16 = (wid == 0) ? q : s_;
  unsigned char* o8 = (wid == 1) ? k8 : v8;

  if (!isfp8) {
#pragma unroll
    for (int mt = 0; mt < 4; ++mt) {
#pragma unroll
      for (int nt = 0; nt < 8; ++nt) {
        int cb = nt * 16 + lg * 4;
        float4 bb = *reinterpret_cast<const float4*>(bias + cb);
        ushort4 u;
        u.x = __builtin_bit_cast(unsigned short, (_Float16)(acc[mt][nt][0] + bb.x));
        u.y = __builtin_bit_cast(unsigned short, (_Float16)(acc[mt][nt][1] + bb.y));
        u.z = __builtin_bit_cast(unsigned short, (_Float16)(acc[mt][nt][2] + bb.z));
        u.w = __builtin_bit_cast(unsigned short, (_Float16)(acc[mt][nt][3] + bb.w));
        int byte = (lr * 256 + cb * 2) ^ ((lr & 7) << 4);
        *reinterpret_cast<ushort4*>(reg + byte) = u;
      }
#pragma unroll
      for (int i = 0; i < 4; ++i) {
        int r = i * 4 + (lane >> 4);
        int byte = (r * 256 + (lane & 15) * 16) ^ ((r & 7) << 4);
        int4 val = *reinterpret_cast<const int4*>(reg + byte);
        size_t row = row0 + mt * 16 + r;
        if (row < (size_t)N)
          *reinterpret_cast<int4*>(o16 + row * CH + (lane & 15) * 8) = val;
      }
    }
  } else {
#pragma unroll
    for (int mt = 0; mt < 4; ++mt) {
#pragma unroll
      for (int nt = 0; nt < 8; ++nt) {
        int cb = nt * 16 + lg * 4;
        float4 bb = *reinterpret_cast<const float4*>(bias + cb);
        unsigned int w = pkfp8<false>(acc[mt][nt][0] + bb.x, acc[mt][nt][1] + bb.y, 0u);
        w = pkfp8<true>(acc[mt][nt][2] + bb.z, acc[mt][nt][3] + bb.w, w);
        int byte = (lr * 128 + cb) ^ ((lr & 7) << 4);
        *reinterpret_cast<unsigned int*>(reg + byte) = w;
      }
#pragma unroll
      for (int i = 0; i < 2; ++i) {
        int r = i * 8 + (lane >> 3);
        int byte = (r * 128 + (lane & 7) * 16) ^ ((r & 7) << 4);
        int4 val = *reinterpret_cast<const int4*>(reg + byte);
        size_t row = row0 + mt * 16 + r;
        if (row < (size_t)N)
          *reinterpret_cast<int4*>(o8 + row * CH + (lane & 7) * 16) = val;
      }
    }
  }
}

// ---------- 3. CSR build over dst (rank trick: deg_rank then atomic-free scatter) ----------
__global__ void deg_rank_kernel(const int* __restrict__ dst, int* __restrict__ deg,
                                unsigned char* __restrict__ rank, int E) {
  for (int e = blockIdx.x * blockDim.x + threadIdx.x; e < E; e += gridDim.x * blockDim.x) {
    rank[e] = (unsigned char)atomicAdd(&deg[dst[e]], 1);
  }
}

__global__ void sum_chunks_kernel(const int* __restrict__ deg, int* __restrict__ chunksums, int N) {
  __shared__ int sd[256];
  int t = threadIdx.x;
  int base = blockIdx.x * 2048;
  int s = 0;
  for (int i = 0; i < 8; ++i) {
    int idx = base + t * 8 + i;
    if (idx < N) s += deg[idx];
  }
  sd[t] = s;
  __syncthreads();
  for (int o = 128; o > 0; o >>= 1) {
    if (t < o) sd[t] += sd[t + o];
    __syncthreads();
  }
  if (t == 0) chunksums[blockIdx.x] = sd[0];
}

// scan_chunks with inlined scan_sums: each block derives its base from chunksums.
__global__ void scan_chunks_kernel(const int* __restrict__ deg, const int* __restrict__ chunksums,
                                   int* __restrict__ rowptr, int N, int nchunks) {
  __shared__ int sd[256];
  __shared__ int base_off;
  int t = threadIdx.x;
  int cb = blockIdx.x;
  int pre = 0;
  for (int i = t; i < cb; i += 256) pre += chunksums[i];
  sd[t] = pre;
  __syncthreads();
  for (int o = 128; o > 0; o >>= 1) {
    if (t < o) sd[t] += sd[t + o];
    __syncthreads();
  }
  if (t == 0) base_off = sd[0];
  __syncthreads();
  int cbase = base_off;
  __syncthreads();  // sd reused below

  int base = cb * 2048;
  int vals[8];
  int s = 0;
  for (int i = 0; i < 8; ++i) {
    int idx = base + t * 8 + i;
    int d = (idx < N) ? deg[idx] : 0;
    vals[i] = s;
    s += d;
  }
  sd[t] = s;
  __syncthreads();
  int mytot = s;
  for (int o = 1; o < 256; o <<= 1) {
    int vprev = (t >= o) ? sd[t - o] : 0;
    __syncthreads();
    sd[t] += vprev;
    __syncthreads();
  }
  int texcl = sd[t] - mytot;
  for (int i = 0; i < 8; ++i) {
    int idx = base + t * 8 + i;
    if (idx < N) rowptr[idx] = cbase + texcl + vals[i];
  }
  if (cb == nchunks - 1 && t == 255) rowptr[N] = cbase + sd[255];
}

__global__ void scatter_kernel(const int* __restrict__ src, const int* __restrict__ dst,
                               const int* __restrict__ rowptr, const unsigned char* __restrict__ rank,
                               int* __restrict__ sorted_src, int E) {
  for (int e = blockIdx.x * blockDim.x + threadIdx.x; e < E; e += gridDim.x * blockDim.x) {
    int d = dst[e];
    int pos = rowptr[d] + (int)rank[e];
    sorted_src[pos] = src[e];
  }
}

// ---------- 4. per-dst softmax (no max; range-safe) + aggregation; fp8 k/v ----------
// 1 wave per node (grid-stride). 8 edges per iteration (2 slots, loads up front).
// conv aliases q: q[n] fully consumed by the owning wave before conv[n] is written.
__global__ __launch_bounds__(256) void attn_kernel(
    const unsigned short* __restrict__ q, const unsigned char* __restrict__ k8,
    const unsigned char* __restrict__ v8, const unsigned short* __restrict__ skp,
    const int* __restrict__ rowptr, const int* __restrict__ sorted_src,
    unsigned short* __restrict__ conv, int N, int nw) {
  int lane = threadIdx.x & 63;
  int g = lane >> 4;
  int s = lane & 15;
  int w0 = blockIdx.x * (blockDim.x >> 6) + (threadIdx.x >> 6);
  const float ASC = 0.17677669529663687f;  // 1/sqrt(32)
  for (int n = w0; n < N; n += nw) {
    int beg = rowptr[n], end = rowptr[n + 1];
    size_t rowb = (size_t)n * CH + s * 8;
    uint4 qr = *reinterpret_cast<const uint4*>(q + rowb);
    f32x2 qv[4];
    {
      f16x2 t0 = __builtin_bit_cast(f16x2, qr.x);
      f16x2 t1 = __builtin_bit_cast(f16x2, qr.y);
      f16x2 t2 = __builtin_bit_cast(f16x2, qr.z);
      f16x2 t3 = __builtin_bit_cast(f16x2, qr.w);
      qv[0] = (f32x2){(float)t0[0] * ASC, (float)t0[1] * ASC};
      qv[1] = (f32x2){(float)t1[0] * ASC, (float)t1[1] * ASC};
      qv[2] = (f32x2){(float)t2[0] * ASC, (float)t2[1] * ASC};
      qv[3] = (f32x2){(float)t3[0] * ASC, (float)t3[1] * ASC};
    }
    float ssum = 0.f;
    f32x2 vA = (f32x2){0.f, 0.f}, vB = vA, vC = vA, vD = vA;
    int nit2 = (end - beg + 7) >> 3;
    unsigned soff = (unsigned)(s * 8);
    for (int it = 0; it < nit2; ++it) {
      int e0 = beg + it * 8 + g;
      int e1 = e0 + 4;
      bool v0 = e0 < end;
      bool v1 = e1 < end;
      unsigned src0 = (unsigned)sorted_src[v0 ? e0 : beg];
      unsigned src1 = (unsigned)sorted_src[v1 ? e1 : beg];
      unsigned sb0 = (src0 << 7) + soff;  // 32-bit offsets: N*128 < 2^31
      unsigned sb1 = (src1 << 7) + soff;
      uint2 kr0 = *reinterpret_cast<const uint2*>(k8 + sb0);
      uint2 vr0 = *reinterpret_cast<const uint2*>(v8 + sb0);
      uint2 kr1 = *reinterpret_cast<const uint2*>(k8 + sb1);
      uint2 vr1 = *reinterpret_cast<const uint2*>(v8 + sb1);
      f32x2 p0 = upkfp8<false>(kr0.x) * qv[0];
      p0 += upkfp8<true>(kr0.x) * qv[1];
      p0 += upkfp8<false>(kr0.y) * qv[2];
      p0 += upkfp8<true>(kr0.y) * qv[3];
      float pa = p0[0] + p0[1];
      f32x2 p1 = upkfp8<false>(kr1.x) * qv[0];
      p1 += upkfp8<true>(kr1.x) * qv[1];
      p1 += upkfp8<false>(kr1.y) * qv[2];
      p1 += upkfp8<true>(kr1.y) * qv[3];
      float pb = p1[0] + p1[1];
      pa += __shfl_xor(pa, 1);
      pb += __shfl_xor(pb, 1);
      pa += __shfl_xor(pa, 2);
      pb += __shfl_xor(pb, 2);
      float ex0 = v0 ? __expf(pa) : 0.f;
      float ex1 = v1 ? __expf(pb) : 0.f;
      ssum += ex0 + ex1;
      f32x2 e20 = (f32x2){ex0, ex0};
      f32x2 e21 = (f32x2){ex1, ex1};
      vA += e20 * upkfp8<false>(vr0.x);
      vB += e20 * upkfp8<true>(vr0.x);
      vC += e20 * upkfp8<false>(vr0.y);
      vD += e20 * upkfp8<true>(vr0.y);
      vA += e21 * upkfp8<false>(vr1.x);
      vB += e21 * upkfp8<true>(vr1.x);
      vC += e21 * upkfp8<false>(vr1.y);
      vD += e21 * upkfp8<true>(vr1.y);
    }
    float va[8] = {vA[0], vA[1], vB[0], vB[1], vC[0], vC[1], vD[0], vD[1]};
#pragma unroll
    for (int msk = 16; msk <= 32; msk <<= 1) {
      ssum += __shfl_xor(ssum, msk);
#pragma unroll
      for (int i = 0; i < 8; ++i) va[i] += __shfl_xor(va[i], msk);
    }
    float inv = (end > beg) ? 1.0f / ssum : 0.f;
    if (g == 0) {
      uint4 sr = *reinterpret_cast<const uint4*>(skp + rowb);
      f16x2 s0 = __builtin_bit_cast(f16x2, sr.x);
      f16x2 s1 = __builtin_bit_cast(f16x2, sr.y);
      f16x2 s2 = __builtin_bit_cast(f16x2, sr.z);
      f16x2 s3 = __builtin_bit_cast(f16x2, sr.w);
      int4 pk;
      pk.x = (int)f2bf(va[0] * inv + (float)s0[0]) | ((int)f2bf(va[1] * inv + (float)s0[1]) << 16);
      pk.y = (int)f2bf(va[2] * inv + (float)s1[0]) | ((int)f2bf(va[3] * inv + (float)s1[1]) << 16);
      pk.z = (int)f2bf(va[4] * inv + (float)s2[0]) | ((int)f2bf(va[5] * inv + (float)s2[1]) << 16);
      pk.w = (int)f2bf(va[6] * inv + (float)s3[0]) | ((int)f2bf(va[7] * inv + (float)s3[1]) << 16);
      *reinterpret_cast<int4*>(conv + rowb) = pk;
    }
  }
}

// ---------- 5. out = conv @ Wfc + bfc + x via MFMA; LDS-staged coalesced epilogue ----------
__global__ __launch_bounds__(256) void final_mfma_kernel(
    const unsigned short* __restrict__ conv, const unsigned short* __restrict__ Wt,
    const float* __restrict__ bfc, const float* __restrict__ x,
    float* __restrict__ outp, int N) {
  __shared__ __align__(16) unsigned short As[64 * 128];
  int t = threadIdx.x;
  int lane = t & 63;
  int wid = t >> 6;
  size_t row0 = (size_t)blockIdx.x * 64;

  for (int i = 0; i < 4; ++i) {
    int c = i * 256 + t;
    int r = c >> 4;
    int kc = (c & 15) * 8;
    int4 pk = make_int4(0, 0, 0, 0);
    if (row0 + r < (size_t)N)
      pk = *reinterpret_cast<const int4*>(conv + (row0 + r) * CH + kc);
    int byte = (r * 256 + kc * 2) ^ ((r & 7) << 4);
    *reinterpret_cast<int4*>((char*)As + byte) = pk;
  }
  __syncthreads();

  const unsigned short* wt = Wt + ((size_t)4 << 14);
  int lr = lane & 15;
  int lg = lane >> 4;

  f32x4 acc[4][2];
#pragma unroll
  for (int mt = 0; mt < 4; ++mt)
#pragma unroll
    for (int i = 0; i < 2; ++i) acc[mt][i] = (f32x4){0.f, 0.f, 0.f, 0.f};

  for (int ks = 0; ks < 4; ++ks) {
    bf16x8 a[4], b[2];
#pragma unroll
    for (int mt = 0; mt < 4; ++mt) {
      int r = mt * 16 + lr;
      int byte = (r * 256 + (ks * 32 + lg * 8) * 2) ^ ((r & 7) << 4);
      a[mt] = *reinterpret_cast<const bf16x8*>((const char*)As + byte);
    }
#pragma unroll
    for (int i = 0; i < 2; ++i) {
      int n = (wid * 2 + i) * 16 + lr;
      b[i] = *reinterpret_cast<const bf16x8*>(wt + n * 128 + ks * 32 + lg * 8);
    }
#pragma unroll
    for (int mt = 0; mt < 4; ++mt)
#pragma unroll
      for (int i = 0; i < 2; ++i)
        acc[mt][i] = __builtin_amdgcn_mfma_f32_16x16x32_bf16(b[i], a[mt], acc[mt][i], 0, 0, 0);
  }

  // stage f32 outputs through per-wave 4KB LDS -> full-line coalesced stores
  __syncthreads();
  char* reg = (char*)As + wid * 4096;
#pragma unroll
  for (int mt = 0; mt < 4; ++mt) {
#pragma unroll
    for (int i = 0; i < 2; ++i) {
      int byte = (lr * 128 + i * 64 + lg * 16) ^ ((lr & 7) << 4);
      *reinterpret_cast<f32x4*>(reg + byte) = acc[mt][i];
    }
#pragma unroll
    for (int i2 = 0; i2 < 2; ++i2) {
      int r = i2 * 8 + (lane >> 3);
      int byte = (r * 128 + (lane & 7) * 16) ^ ((r & 7) << 4);
      f32x4 val = *reinterpret_cast<const f32x4*>(reg + byte);
      int ch = wid * 32 + (lane & 7) * 4;
      size_t row = row0 + mt * 16 + r;
      if (row < (size_t)N) {
        float4 bb = *reinterpret_cast<const float4*>(bfc + ch);
        float4 rx = *reinterpret_cast<const float4*>(x + row * CH + ch);
        float4 o;
        o.x = val[0] + bb.x + rx.x;
        o.y = val[1] + bb.y + rx.y;
        o.z = val[2] + bb.z + rx.z;
        o.w = val[3] + bb.w + rx.w;
        *reinterpret_cast<float4*>(outp + row * CH + ch) = o;
      }
    }
  }
}

// ---------------------------------------------------------------
extern "C" void kernel_launch(void* const* d_in, const int* in_sizes, int n_in,
                              void* d_out, int out_size, void* d_ws, size_t ws_size,
                              hipStream_t stream) {
  const float* x = (const float*)d_in[0];
  const int* ei = (const int*)d_in[1];
  const float* gamma = (const float*)d_in[2];
  const float* beta = (const float*)d_in[3];
  const float* Wq = (const float*)d_in[4];
  const float* bq = (const float*)d_in[5];
  const float* Wk = (const float*)d_in[6];
  const float* bk = (const float*)d_in[7];
  const float* Wv = (const float*)d_in[8];
  const float* bv = (const float*)d_in[9];
  const float* Ws = (const float*)d_in[10];
  const float* bs = (const float*)d_in[11];
  const float* Wfc = (const float*)d_in[12];
  const float* bfc = (const float*)d_in[13];

  const int N = in_sizes[0] / CH;
  const int E = in_sizes[1] / 2;
  const int* srcp = ei;
  const int* dstp = ei + E;
  float* outp = (float*)d_out;

  char* wsb = (char*)d_ws;
  size_t off = 0;
  auto take = [&](size_t bytes) -> void* {
    void* p = wsb + off;
    off = (off + bytes + 255) & ~(size_t)255;
    return p;
  };
  float* stats = (float*)take(256 * 4);
  unsigned short* Wt = (unsigned short*)take((size_t)5 * 16384 * 2);
  unsigned short* qb = (unsigned short*)take((size_t)N * CH * 2);  // conv aliases this
  unsigned char* kb8 = (unsigned char*)take((size_t)N * CH);
  unsigned char* vb8 = (unsigned char*)take((size_t)N * CH);
  unsigned short* sb = (unsigned short*)take((size_t)N * CH * 2);
  int* deg = (int*)take((size_t)N * 4);
  unsigned char* rank = (unsigned char*)take((size_t)E);
  int* rowptr = (int*)take((size_t)(N + 1) * 4);
  int nchunks = (N + 2047) / 2048;
  int* chunksums = (int*)take((size_t)nchunks * 4);
  int* sorted_src = (int*)take((size_t)E * 4);
  unsigned short* convb = qb;  // alias: q consumed before conv written (same wave, same row)

  (void)hipMemsetAsync(stats, 0, 256 * 4, stream);
  (void)hipMemsetAsync(deg, 0, (size_t)N * 4, stream);

  bn_stats_kernel<<<512, 256, 0, stream>>>(x, stats, N);
  pack_w_kernel<<<320, 256, 0, stream>>>(Wq, Wk, Wv, Ws, Wfc, Wt);

  int nblk = (N + 63) / 64;
  proj_mfma_kernel<<<nblk, 256, 0, stream>>>(x, stats, gamma, beta, Wt, bq, bk, bv, bs, qb, kb8,
                                             vb8, sb, N);

  deg_rank_kernel<<<2048, 256, 0, stream>>>(dstp, deg, rank, E);
  sum_chunks_kernel<<<nchunks, 256, 0, stream>>>(deg, chunksums, N);
  scan_chunks_kernel<<<nchunks, 256, 0, stream>>>(deg, chunksums, rowptr, N, nchunks);
  scatter_kernel<<<2048, 256, 0, stream>>>(srcp, dstp, rowptr, rank, sorted_src, E);

  int ablocks = 4096;
  attn_kernel<<<ablocks, 256, 0, stream>>>(qb, kb8, vb8, sb, rowptr, sorted_src, convb, N,
                                           ablocks * 4);
  final_mfma_kernel<<<nblk, 256, 0, stream>>>(convb, Wt, bfc, x, outp, N);
}